// Round 2
// baseline (4831.036 us; speedup 1.0000x reference)
//
#include <hip/hip_runtime.h>
#include <hip/hip_bf16.h>

constexpr int CB = 64;     // batch
constexpr int CS = 512;    // seq
constexpr int CDE = 384;   // embed dim
constexpr int CD = 1024;   // model dim
constexpr int CM = 16;     // hist depth
constexpr int CH = 4;      // neuron hidden
constexpr int CNH = 8;     // heads
constexpr int CDH = 128;   // head dim
constexpr int CDA = 512;
constexpr int CDO = 512;
constexpr int CT = 16;     // T_MAX
constexpr int CTP1 = 17;

__device__ __forceinline__ float gelu_exact(float x) {
    return 0.5f * x * (1.0f + erff(x * 0.70710678118654752440f));
}
__device__ __forceinline__ float softplusf(float x) {
    return fmaxf(x, 0.0f) + log1pf(expf(-fabsf(x)));
}
__device__ __forceinline__ float us2f(unsigned short u) {
    union { unsigned int i; float f; } c; c.i = ((unsigned int)u) << 16; return c.f;
}
__device__ __forceinline__ unsigned short f2us(float x) {
    __hip_bfloat16 b = __float2bfloat16(x);  // RNE
    union { __hip_bfloat16 b; unsigned short u; } c; c.b = b; return c.u;
}

template <typename T>
__device__ __forceinline__ float4 ld4(const T* p);
template <>
__device__ __forceinline__ float4 ld4<float>(const float* p) { return *(const float4*)p; }
template <>
__device__ __forceinline__ float4 ld4<unsigned short>(const unsigned short* p) {
    ushort4 u = *(const ushort4*)p;
    return make_float4(us2f(u.x), us2f(u.y), us2f(u.z), us2f(u.w));
}
__device__ __forceinline__ void st4(float* p, float4 v) { *(float4*)p = v; }
__device__ __forceinline__ void st4(unsigned short* p, float4 v) {
    ushort4 u = make_ushort4(f2us(v.x), f2us(v.y), f2us(v.z), f2us(v.w));
    *(ushort4*)p = u;
}

// ---------------------------------------------------------------------------
// Generic C[M,N] = A[M,K] @ W[N,K]^T (+bias when gridDim.z==1).
// 64x64 tile, 256 threads, 4x4 microtile, K-chunk per blockIdx.z (partial out).
// ---------------------------------------------------------------------------
template <typename TA, typename TW, typename TC>
__global__ __launch_bounds__(256) void gemm_tn(
    const TA* __restrict__ A, const TW* __restrict__ W,
    const float* __restrict__ bias, TC* __restrict__ C,
    int N, int K, int kc) {
    __shared__ __align__(16) float As[16][68];
    __shared__ __align__(16) float Ws[16][68];
    const int tid = threadIdx.x;
    const int row0 = blockIdx.x << 6;
    const int col0 = blockIdx.y << 6;
    const int kbeg = blockIdx.z * kc;
    const int lr = tid >> 2;
    const int lk = (tid & 3) << 2;
    const TA* Ap = A + (size_t)(row0 + lr) * K + kbeg + lk;
    const TW* Wr = W + (size_t)(col0 + lr) * K + kbeg + lk;
    const int tx = tid & 15, ty = tid >> 4;
    float acc[4][4];
#pragma unroll
    for (int i = 0; i < 4; i++)
#pragma unroll
        for (int j = 0; j < 4; j++) acc[i][j] = 0.0f;

    for (int k0 = 0; k0 < kc; k0 += 16) {
        float4 a4 = ld4(Ap + k0);
        float4 w4 = ld4(Wr + k0);
        As[lk + 0][lr] = a4.x; As[lk + 1][lr] = a4.y;
        As[lk + 2][lr] = a4.z; As[lk + 3][lr] = a4.w;
        Ws[lk + 0][lr] = w4.x; Ws[lk + 1][lr] = w4.y;
        Ws[lk + 2][lr] = w4.z; Ws[lk + 3][lr] = w4.w;
        __syncthreads();
#pragma unroll
        for (int kk = 0; kk < 16; kk++) {
            float4 av = *(const float4*)&As[kk][ty << 2];
            float4 wv = *(const float4*)&Ws[kk][tx << 2];
            acc[0][0] += av.x * wv.x; acc[0][1] += av.x * wv.y;
            acc[0][2] += av.x * wv.z; acc[0][3] += av.x * wv.w;
            acc[1][0] += av.y * wv.x; acc[1][1] += av.y * wv.y;
            acc[1][2] += av.y * wv.z; acc[1][3] += av.y * wv.w;
            acc[2][0] += av.z * wv.x; acc[2][1] += av.z * wv.y;
            acc[2][2] += av.z * wv.z; acc[2][3] += av.z * wv.w;
            acc[3][0] += av.w * wv.x; acc[3][1] += av.w * wv.y;
            acc[3][2] += av.w * wv.z; acc[3][3] += av.w * wv.w;
        }
        __syncthreads();
    }

    const int c0 = col0 + (tx << 2);
    if (gridDim.z == 1) {
#pragma unroll
        for (int i = 0; i < 4; i++) {
            size_t r = (size_t)(row0 + (ty << 2) + i);
            float4 o;
            o.x = acc[i][0] + bias[c0 + 0];
            o.y = acc[i][1] + bias[c0 + 1];
            o.z = acc[i][2] + bias[c0 + 2];
            o.w = acc[i][3] + bias[c0 + 3];
            st4(C + r * N + c0, o);
        }
    } else {
        TC* Cp = C + (size_t)blockIdx.z * ((size_t)64 * N);
#pragma unroll
        for (int i = 0; i < 4; i++) {
            size_t r = (size_t)(row0 + (ty << 2) + i);
            st4(Cp + r * N + c0, make_float4(acc[i][0], acc[i][1], acc[i][2], acc[i][3]));
        }
    }
}

// Sum 8 K-split partials + bias (+optional gelu); write at column offset of a
// row of width CW (lets Wo-proj write the second half of `combined`).
template <int ACT>
__global__ __launch_bounds__(256) void reduce8_kernel(
    const float* __restrict__ P, const float* __restrict__ bias,
    float* __restrict__ C, int N, int coff, int CW) {
    int i = blockIdx.x * 256 + threadIdx.x;  // over 64*N
    int row = i / N;
    int col = i - row * N;
    size_t stride = (size_t)64 * N;
    float s = 0.0f;
#pragma unroll
    for (int z = 0; z < 8; z++) s += P[(size_t)z * stride + (size_t)row * N + col];
    s += bias[col];
    if (ACT) s = gelu_exact(s);
    C[(size_t)row * CW + coff + col] = s;
}

// LayerNorm + GELU, in place on bf16 h rows (h already includes bp bias).
__global__ __launch_bounds__(256) void ln_gelu_kernel(
    unsigned short* __restrict__ hc, const float* __restrict__ g,
    const float* __restrict__ bb) {
    __shared__ float sred[4];
    const int tid = threadIdx.x;
    size_t base = (size_t)blockIdx.x * CD;
    float4 x = ld4(hc + base + tid * 4);
    float s = x.x + x.y + x.z + x.w;
#pragma unroll
    for (int off = 32; off; off >>= 1) s += __shfl_down(s, off, 64);
    if ((tid & 63) == 0) sred[tid >> 6] = s;
    __syncthreads();
    float mu = (sred[0] + sred[1] + sred[2] + sred[3]) * (1.0f / 1024.0f);
    float d0 = x.x - mu, d1 = x.y - mu, d2 = x.z - mu, d3 = x.w - mu;
    float sq = d0 * d0 + d1 * d1 + d2 * d2 + d3 * d3;
    __syncthreads();
#pragma unroll
    for (int off = 32; off; off >>= 1) sq += __shfl_down(sq, off, 64);
    if ((tid & 63) == 0) sred[tid >> 6] = sq;
    __syncthreads();
    float var = (sred[0] + sred[1] + sred[2] + sred[3]) * (1.0f / 1024.0f);
    float rs = 1.0f / sqrtf(var + 1e-5f);
    float4 gv = ((const float4*)g)[tid];
    float4 bv = ((const float4*)bb)[tid];
    float4 o;
    o.x = gelu_exact(d0 * rs * gv.x + bv.x);
    o.y = gelu_exact(d1 * rs * gv.y + bv.y);
    o.z = gelu_exact(d2 * rs * gv.z + bv.z);
    o.w = gelu_exact(d3 * rs * gv.w + bv.w);
    st4(hc + base + tid * 4, o);
}

// zbuf[:,0,:]=z_init, rest 0; hist = broadcast hist_init.
__global__ __launch_bounds__(256) void init_kernel(
    const float* __restrict__ z_init, const float* __restrict__ hist_init,
    float* __restrict__ zbuf, float* __restrict__ hist) {
    int i = blockIdx.x * 256 + threadIdx.x;
    if (i < CB * CTP1 * CD) {
        int rem = i % (CTP1 * CD);
        int ts = rem / CD;
        int d = rem - ts * CD;
        zbuf[i] = (ts == 0) ? z_init[d] : 0.0f;
    }
    if (i < CB * CD * CM) {
        hist[i] = hist_init[i % (CD * CM)];
    }
}

// s_act, s_out for step t; also copies z = zbuf[:,t,:] into combined[:, :D].
__global__ __launch_bounds__(256) void sync_kernel(
    const float* __restrict__ zbuf,
    const float* __restrict__ decay_a, const float* __restrict__ decay_o,
    const int* __restrict__ iia, const int* __restrict__ jja,
    const int* __restrict__ iio, const int* __restrict__ jjo,
    float* __restrict__ s_act, float* __restrict__ s_out,
    float* __restrict__ combined, int t) {
    int b = blockIdx.x >> 2;
    int sg = ((blockIdx.x & 3) << 8) + threadIdx.x;  // 0..1023
    const float* zb = zbuf + (size_t)b * CTP1 * CD;
    combined[(size_t)b * (2 * CD) + sg] = zb[(size_t)t * CD + sg];
    float soft;
    int ii, jj;
    if (sg < CDA) {
        soft = softplusf(decay_a[sg]);
        ii = iia[sg]; jj = jja[sg];
    } else {
        int s2 = sg - CDA;
        soft = softplusf(decay_o[s2]);
        ii = iio[s2]; jj = jjo[s2];
    }
    float num = 0.0f, den = 0.0f;
    for (int ts = 0; ts <= t; ts++) {
        float w = expf(-soft * (float)(t - ts));
        num += zb[(size_t)ts * CD + ii] * zb[(size_t)ts * CD + jj] * w;
        den += w * w;
    }
    float val = num / sqrtf(den + 1e-8f);
    if (sg < CDA) s_act[b * CDA + sg] = val;
    else s_out[b * CDO + (sg - CDA)] = val;
}

// One block per (b,h): scores over S=512, softmax, P@V. k/v are bf16.
__global__ __launch_bounds__(256) void attn_kernel(
    const float* __restrict__ qh, const unsigned short* __restrict__ kb,
    const unsigned short* __restrict__ vb, float* __restrict__ attn_out) {
    __shared__ float qv[CDH];
    __shared__ float att[CS];
    __shared__ float red[4];
    __shared__ float pv[2][CDH];
    const int tid = threadIdx.x;
    const int b = blockIdx.x >> 3, h = blockIdx.x & 7;
    if (tid < CDH) qv[tid] = qh[(size_t)b * CD + h * CDH + tid];
    __syncthreads();
    const float scale = 0.08838834764831845f;  // 1/sqrt(128)
    float sc0, sc1;
    {
        const unsigned short* kr0 = kb + ((size_t)(b * CS) + tid) * CD + h * CDH;
        const unsigned short* kr1 = kr0 + (size_t)256 * CD;
        float a0 = 0.0f, a1 = 0.0f;
#pragma unroll 8
        for (int d2 = 0; d2 < CDH; d2 += 4) {
            float4 k0 = ld4(kr0 + d2);
            float4 k1 = ld4(kr1 + d2);
            a0 += k0.x * qv[d2] + k0.y * qv[d2 + 1] + k0.z * qv[d2 + 2] + k0.w * qv[d2 + 3];
            a1 += k1.x * qv[d2] + k1.y * qv[d2 + 1] + k1.z * qv[d2 + 2] + k1.w * qv[d2 + 3];
        }
        sc0 = a0 * scale;
        sc1 = a1 * scale;
    }
    float mx = fmaxf(sc0, sc1);
#pragma unroll
    for (int off = 32; off; off >>= 1) mx = fmaxf(mx, __shfl_down(mx, off, 64));
    if ((tid & 63) == 0) red[tid >> 6] = mx;
    __syncthreads();
    mx = fmaxf(fmaxf(red[0], red[1]), fmaxf(red[2], red[3]));
    float e0 = expf(sc0 - mx), e1 = expf(sc1 - mx);
    att[tid] = e0;
    att[tid + 256] = e1;
    float sm = e0 + e1;
#pragma unroll
    for (int off = 32; off; off >>= 1) sm += __shfl_down(sm, off, 64);
    __syncthreads();  // done reading red(max); att writes visible after next sync
    if ((tid & 63) == 0) red[tid >> 6] = sm;
    __syncthreads();
    float inv = 1.0f / (red[0] + red[1] + red[2] + red[3]);
    const int d = tid & 127, half = tid >> 7;
    const unsigned short* vr = vb + ((size_t)(b * CS) + half * 256) * CD + h * CDH + d;
    float acc = 0.0f;
    for (int s2 = 0; s2 < 256; s2++) {
        acc += att[half * 256 + s2] * us2f(vr[(size_t)s2 * CD]);
    }
    pv[half][d] = acc;
    __syncthreads();
    if (tid < CDH)
        attn_out[(size_t)b * CD + h * CDH + tid] = (pv[0][tid] + pv[1][tid]) * inv;
}

// hist shift+append, 3 tiny per-(b,d) einsums, write z_new into zbuf[:,t+1,:].
__global__ __launch_bounds__(256) void neuron_kernel(
    const float* __restrict__ pre, float* __restrict__ hist,
    const float* __restrict__ Wn1, const float* __restrict__ bn1,
    const float* __restrict__ Wn2, const float* __restrict__ bn2,
    const float* __restrict__ Wn3, const float* __restrict__ bn3,
    float* __restrict__ zbuf, int t) {
    int idx = blockIdx.x * 256 + threadIdx.x;  // 0..65535 = (b,d)
    int b = idx >> 10, d = idx & 1023;
    float hv[CM];
    float* hp = hist + (size_t)idx * CM;
#pragma unroll
    for (int m = 0; m < CM - 1; m++) hv[m] = hp[m + 1];
    hv[CM - 1] = pre[idx];
#pragma unroll
    for (int m = 0; m < CM; m++) hp[m] = hv[m];
    float x1[CH];
#pragma unroll
    for (int hh = 0; hh < CH; hh++) {
        const float* w = Wn1 + ((size_t)d * CH + hh) * CM;
        float s = bn1[d * CH + hh];
#pragma unroll
        for (int m = 0; m < CM; m++) s += hv[m] * w[m];
        x1[hh] = gelu_exact(s);
    }
    float x2[CH];
#pragma unroll
    for (int g = 0; g < CH; g++) {
        float s = bn2[d * CH + g];
#pragma unroll
        for (int hh = 0; hh < CH; hh++) s += x1[hh] * Wn2[((size_t)d * CH + g) * CH + hh];
        x2[g] = gelu_exact(s);
    }
    float z = bn3[d];
#pragma unroll
    for (int hh = 0; hh < CH; hh++) z += x2[hh] * Wn3[d * CH + hh];
    zbuf[((size_t)b * CTP1 + (t + 1)) * CD + d] = z;
}

// One block per b: hh = gelu(s_out@Wh1.T+bh1); out[b,t] = hh@Wh2.T + bh2.
__global__ __launch_bounds__(256) void logits_kernel(
    const float* __restrict__ s_out, const float* __restrict__ Wh1,
    const float* __restrict__ bh1, const float* __restrict__ Wh2,
    const float* __restrict__ bh2, float* __restrict__ out, int t) {
    __shared__ float so[CDO];
    __shared__ float hh[CDO];
    __shared__ float red[4];
    const int b = blockIdx.x, tid = threadIdx.x;
    ((float2*)so)[tid] = ((const float2*)(s_out + (size_t)b * CDO))[tid];
    __syncthreads();
#pragma unroll
    for (int p = 0; p < 2; p++) {
        int j = tid + p * 256;
        const float* w = Wh1 + (size_t)j * CDO;
        float s = bh1[j];
#pragma unroll 4
        for (int k2 = 0; k2 < CDO; k2 += 4) {
            float4 wv = *(const float4*)(w + k2);
            s += wv.x * so[k2] + wv.y * so[k2 + 1] + wv.z * so[k2 + 2] + wv.w * so[k2 + 3];
        }
        hh[j] = gelu_exact(s);
    }
    __syncthreads();
    float part = hh[tid] * Wh2[tid] + hh[tid + 256] * Wh2[tid + 256];
#pragma unroll
    for (int off = 32; off; off >>= 1) part += __shfl_down(part, off, 64);
    if ((tid & 63) == 0) red[tid >> 6] = part;
    __syncthreads();
    if (tid == 0) out[b * CT + t] = red[0] + red[1] + red[2] + red[3] + bh2[0];
}

// Writes v to all outputs; v encodes ws_size in MB so a failure is decodable.
__global__ void sentinel_kernel(float* out, float v) {
    int i = blockIdx.x * 256 + threadIdx.x;
    if (i < CB * CT) out[i] = v;
}

extern "C" void kernel_launch(void* const* d_in, const int* in_sizes, int n_in,
                              void* d_out, int out_size, void* d_ws, size_t ws_size,
                              hipStream_t stream) {
    const float* emb = (const float*)d_in[0];
    const float* Wp = (const float*)d_in[1];
    const float* bp = (const float*)d_in[2];
    const float* ln_g = (const float*)d_in[3];
    const float* ln_b = (const float*)d_in[4];
    const float* decay_a = (const float*)d_in[5];
    const float* decay_o = (const float*)d_in[6];
    const float* Wq = (const float*)d_in[7];
    const float* bq = (const float*)d_in[8];
    const float* Wqkv = (const float*)d_in[9];
    const float* bqkv = (const float*)d_in[10];
    const float* Wo = (const float*)d_in[11];
    const float* bo = (const float*)d_in[12];
    const float* Ws1 = (const float*)d_in[13];
    const float* bs1 = (const float*)d_in[14];
    const float* Ws2 = (const float*)d_in[15];
    const float* bs2 = (const float*)d_in[16];
    const float* Wn1 = (const float*)d_in[17];
    const float* bn1 = (const float*)d_in[18];
    const float* Wn2 = (const float*)d_in[19];
    const float* bn2 = (const float*)d_in[20];
    const float* Wn3 = (const float*)d_in[21];
    const float* bn3 = (const float*)d_in[22];
    const float* Wh1 = (const float*)d_in[23];
    const float* bh1 = (const float*)d_in[24];
    const float* Wh2 = (const float*)d_in[25];
    const float* bh2 = (const float*)d_in[26];
    const float* z_init = (const float*)d_in[27];
    const float* hist_init = (const float*)d_in[28];
    const int* iia = (const int*)d_in[29];
    const int* jja = (const int*)d_in[30];
    const int* iio = (const int*)d_in[31];
    const int* jjo = (const int*)d_in[32];
    float* out = (float*)d_out;

    char* wsb = (char*)d_ws;
    size_t off = 0;
    auto alloc = [&](size_t bytes) {
        void* p = wsb + off;
        off += (bytes + 255) & ~(size_t)255;
        return p;
    };
    // bf16 big buffers (the memory fix): ctx holds bf16 h, then LN'd in place.
    unsigned short* ctx  = (unsigned short*)alloc((size_t)CB * CS * CD * 2);
    unsigned short* kbuf = (unsigned short*)alloc((size_t)CB * CS * CD * 2);
    unsigned short* vbuf = (unsigned short*)alloc((size_t)CB * CS * CD * 2);
    float* zbuf = (float*)alloc((size_t)CB * CTP1 * CD * 4);
    float* hist = (float*)alloc((size_t)CB * CD * CM * 4);
    float* s_act = (float*)alloc((size_t)CB * CDA * 4);
    float* s_out = (float*)alloc((size_t)CB * CDO * 4);
    float* qbuf = (float*)alloc((size_t)CB * CD * 4);
    float* qh = (float*)alloc((size_t)CB * CD * 4);
    float* attn_out = (float*)alloc((size_t)CB * CD * 4);
    float* combined = (float*)alloc((size_t)CB * 2 * CD * 4);
    float* pre1 = (float*)alloc((size_t)CB * 2 * CD * 4);
    float* pre = (float*)alloc((size_t)CB * CD * 4);
    float* P = (float*)alloc((size_t)8 * 64 * 2048 * 4);

    if (off > ws_size) {
        // Encode available MB in the sentinel so the failed absmax reveals ws_size.
        sentinel_kernel<<<dim3(4), dim3(256), 0, stream>>>(out, -(float)(ws_size >> 20));
        return;
    }

    // ---- Phase A ----
    gemm_tn<float, float, unsigned short>
        <<<dim3(512, 16, 1), 256, 0, stream>>>(emb, Wp, bp, ctx, CD, CDE, CDE);
    ln_gelu_kernel<<<dim3(CB * CS), 256, 0, stream>>>(ctx, ln_g, ln_b);
    gemm_tn<unsigned short, float, unsigned short>
        <<<dim3(512, 16, 1), 256, 0, stream>>>(ctx, Wqkv + (size_t)CD * CD, bqkv + CD, kbuf, CD, CD, CD);
    gemm_tn<unsigned short, float, unsigned short>
        <<<dim3(512, 16, 1), 256, 0, stream>>>(ctx, Wqkv + (size_t)2 * CD * CD, bqkv + 2 * CD, vbuf, CD, CD, CD);
    init_kernel<<<dim3(4352), 256, 0, stream>>>(z_init, hist_init, zbuf, hist);

    // ---- Phase B: 16 sequential steps ----
    for (int t = 0; t < CT; t++) {
        sync_kernel<<<dim3(256), 256, 0, stream>>>(zbuf, decay_a, decay_o, iia, jja, iio, jjo,
                                                   s_act, s_out, combined, t);
        // q = s_act @ Wq.T + bq
        gemm_tn<float, float, float><<<dim3(1, 16, 8), 256, 0, stream>>>(s_act, Wq, nullptr, P, CD, CDA, CDA / 8);
        reduce8_kernel<0><<<dim3(256), 256, 0, stream>>>(P, bq, qbuf, CD, 0, CD);
        // qh = q @ Wq3.T + bq3
        gemm_tn<float, float, float><<<dim3(1, 16, 8), 256, 0, stream>>>(qbuf, Wqkv, nullptr, P, CD, CD, CD / 8);
        reduce8_kernel<0><<<dim3(256), 256, 0, stream>>>(P, bqkv, qh, CD, 0, CD);
        // attention
        attn_kernel<<<dim3(CB * CNH), 256, 0, stream>>>(qh, kbuf, vbuf, attn_out);
        // attn_out @ Wo.T + bo -> combined[:, D:]
        gemm_tn<float, float, float><<<dim3(1, 16, 8), 256, 0, stream>>>(attn_out, Wo, nullptr, P, CD, CD, CD / 8);
        reduce8_kernel<0><<<dim3(256), 256, 0, stream>>>(P, bo, combined, CD, CD, 2 * CD);
        // pre1 = gelu(combined @ Ws1.T + bs1)
        gemm_tn<float, float, float><<<dim3(1, 32, 8), 256, 0, stream>>>(combined, Ws1, nullptr, P, 2 * CD, 2 * CD, 2 * CD / 8);
        reduce8_kernel<1><<<dim3(512), 256, 0, stream>>>(P, bs1, pre1, 2 * CD, 0, 2 * CD);
        // pre = pre1 @ Ws2.T + bs2
        gemm_tn<float, float, float><<<dim3(1, 16, 8), 256, 0, stream>>>(pre1, Ws2, nullptr, P, CD, 2 * CD, 2 * CD / 8);
        reduce8_kernel<0><<<dim3(256), 256, 0, stream>>>(P, bs2, pre, CD, 0, CD);
        // hist update + neuron MLP -> zbuf[:, t+1]
        neuron_kernel<<<dim3(256), 256, 0, stream>>>(pre, hist, Wn1, bn1, Wn2, bn2, Wn3, bn3, zbuf, t);
        // logits for this step
        logits_kernel<<<dim3(CB), 256, 0, stream>>>(s_out, Wh1, bh1, Wh2, bh2, out, t);
    }
}

// Round 3
// 2626.068 us; speedup vs baseline: 1.8396x; 1.8396x over previous
//
#include <hip/hip_runtime.h>
#include <hip/hip_bf16.h>

constexpr int CB = 64;     // batch
constexpr int CS = 512;    // seq
constexpr int CDE = 384;   // embed dim
constexpr int CD = 1024;   // model dim
constexpr int CM = 16;     // hist depth
constexpr int CH = 4;      // neuron hidden
constexpr int CNH = 8;     // heads
constexpr int CDH = 128;   // head dim
constexpr int CDA = 512;
constexpr int CDO = 512;
constexpr int CT = 16;     // T_MAX
constexpr int CTP1 = 17;

typedef __attribute__((ext_vector_type(8))) short bfrag;   // 8 bf16 (4 VGPRs)
typedef __attribute__((ext_vector_type(4))) float ffrag;   // MFMA accumulator

__device__ __forceinline__ float gelu_exact(float x) {
    return 0.5f * x * (1.0f + erff(x * 0.70710678118654752440f));
}
__device__ __forceinline__ float softplusf(float x) {
    return fmaxf(x, 0.0f) + log1pf(expf(-fabsf(x)));
}
__device__ __forceinline__ float us2f(unsigned short u) {
    union { unsigned int i; float f; } c; c.i = ((unsigned int)u) << 16; return c.f;
}
__device__ __forceinline__ unsigned short f2us(float x) {
    __hip_bfloat16 b = __float2bfloat16(x);  // RNE
    union { __hip_bfloat16 b; unsigned short u; } c; c.b = b; return c.u;
}

template <typename T>
__device__ __forceinline__ float4 ld4(const T* p);
template <>
__device__ __forceinline__ float4 ld4<float>(const float* p) { return *(const float4*)p; }
template <>
__device__ __forceinline__ float4 ld4<unsigned short>(const unsigned short* p) {
    ushort4 u = *(const ushort4*)p;
    return make_float4(us2f(u.x), us2f(u.y), us2f(u.z), us2f(u.w));
}
__device__ __forceinline__ void st4(float* p, float4 v) { *(float4*)p = v; }
__device__ __forceinline__ void st4(unsigned short* p, float4 v) {
    ushort4 u = make_ushort4(f2us(v.x), f2us(v.y), f2us(v.z), f2us(v.w));
    *(ushort4*)p = u;
}

// 8 contiguous elements -> 8 bf16 (converting if fp32 source)
__device__ __forceinline__ bfrag ld8bf(const unsigned short* p) {
    return *(const bfrag*)p;
}
__device__ __forceinline__ bfrag ld8bf(const float* p) {
    float4 a = *(const float4*)p;
    float4 b = *(const float4*)(p + 4);
    bfrag v;
    v[0] = (short)f2us(a.x); v[1] = (short)f2us(a.y);
    v[2] = (short)f2us(a.z); v[3] = (short)f2us(a.w);
    v[4] = (short)f2us(b.x); v[5] = (short)f2us(b.y);
    v[6] = (short)f2us(b.z); v[7] = (short)f2us(b.w);
    return v;
}

// ---------------------------------------------------------------------------
// MFMA GEMM: C[M,N](bf16) = A[M,K] @ W[N,K]^T + bias.
// 128x128 tile, 256 threads (4 waves, each a 64x64 sub-tile of 4x4 16x16 frags),
// BK=64, XOR-swizzled LDS (chunk ^= row&7) so ds_read_b128 is 2-way (free).
// A may be fp32 or bf16; W is fp32; both staged to LDS as bf16.
// ---------------------------------------------------------------------------
template <typename TA>
__global__ __launch_bounds__(256) void gemm_mfma(
    const TA* __restrict__ A, const float* __restrict__ W,
    const float* __restrict__ bias, unsigned short* __restrict__ C,
    int N, int K) {
    __shared__ __align__(16) char smem[32768];  // A tile 16KB | B tile 16KB
    char* As = smem;
    char* Bs = smem + 16384;
    const int tid = threadIdx.x;
    const int row0 = blockIdx.x << 7;
    const int col0 = blockIdx.y << 7;
    const int lane = tid & 63;
    const int wid = tid >> 6;
    const int wr = wid >> 1, wc = wid & 1;

    // staging geometry: per issue i (0..3), thread owns (row = i*32 + tid/8,
    // logical chunk c = tid&7); phys chunk = c ^ (row&7).
    const int srow_l = tid >> 3;     // 0..31
    const int schunk = tid & 7;

    ffrag acc[4][4];
#pragma unroll
    for (int m = 0; m < 4; m++)
#pragma unroll
        for (int n = 0; n < 4; n++) acc[m][n] = (ffrag)0.0f;

    for (int k0 = 0; k0 < K; k0 += 64) {
        bfrag va[4], vb[4];
#pragma unroll
        for (int i = 0; i < 4; i++) {
            int r = i * 32 + srow_l;
            va[i] = ld8bf(A + (size_t)(row0 + r) * K + k0 + schunk * 8);
            vb[i] = ld8bf(W + (size_t)(col0 + r) * K + k0 + schunk * 8);
        }
#pragma unroll
        for (int i = 0; i < 4; i++) {
            int r = i * 32 + srow_l;
            int pc = schunk ^ (r & 7);
            *(bfrag*)(As + r * 128 + pc * 16) = va[i];
            *(bfrag*)(Bs + r * 128 + pc * 16) = vb[i];
        }
        __syncthreads();
#pragma unroll
        for (int s = 0; s < 2; s++) {
            bfrag af[4], bf[4];
#pragma unroll
            for (int m = 0; m < 4; m++) {
                int r = wr * 64 + m * 16 + (lane & 15);
                int chunk = (s * 4 + (lane >> 4)) ^ (r & 7);
                af[m] = *(const bfrag*)(As + r * 128 + chunk * 16);
            }
#pragma unroll
            for (int n = 0; n < 4; n++) {
                int r = wc * 64 + n * 16 + (lane & 15);
                int chunk = (s * 4 + (lane >> 4)) ^ (r & 7);
                bf[n] = *(const bfrag*)(Bs + r * 128 + chunk * 16);
            }
#pragma unroll
            for (int m = 0; m < 4; m++)
#pragma unroll
                for (int n = 0; n < 4; n++)
                    acc[m][n] = __builtin_amdgcn_mfma_f32_16x16x32_bf16(
                        af[m], bf[n], acc[m][n], 0, 0, 0);
        }
        __syncthreads();
    }

    // epilogue: C/D layout col=lane&15, row=(lane>>4)*4+reg  [m89/m91]
#pragma unroll
    for (int n = 0; n < 4; n++) {
        int col = col0 + wc * 64 + n * 16 + (lane & 15);
        float bv = bias[col];
#pragma unroll
        for (int m = 0; m < 4; m++) {
            int rbase = row0 + wr * 64 + m * 16 + ((lane >> 4) << 2);
#pragma unroll
            for (int j = 0; j < 4; j++) {
                C[(size_t)(rbase + j) * N + col] = f2us(acc[m][n][j] + bv);
            }
        }
    }
}

// ---------------------------------------------------------------------------
// fp32 vector-ALU GEMM (phase-B skinny matmuls): C[M,N] = A[M,K]@W[N,K]^T.
// ---------------------------------------------------------------------------
__global__ __launch_bounds__(256) void gemm_tn(
    const float* __restrict__ A, const float* __restrict__ W,
    const float* __restrict__ bias, float* __restrict__ C,
    int N, int K, int kc) {
    __shared__ __align__(16) float As[16][68];
    __shared__ __align__(16) float Ws[16][68];
    const int tid = threadIdx.x;
    const int row0 = blockIdx.x << 6;
    const int col0 = blockIdx.y << 6;
    const int kbeg = blockIdx.z * kc;
    const int lr = tid >> 2;
    const int lk = (tid & 3) << 2;
    const float* Ap = A + (size_t)(row0 + lr) * K + kbeg + lk;
    const float* Wr = W + (size_t)(col0 + lr) * K + kbeg + lk;
    const int tx = tid & 15, ty = tid >> 4;
    float acc[4][4];
#pragma unroll
    for (int i = 0; i < 4; i++)
#pragma unroll
        for (int j = 0; j < 4; j++) acc[i][j] = 0.0f;

    for (int k0 = 0; k0 < kc; k0 += 16) {
        float4 a4 = *(const float4*)(Ap + k0);
        float4 w4 = *(const float4*)(Wr + k0);
        As[lk + 0][lr] = a4.x; As[lk + 1][lr] = a4.y;
        As[lk + 2][lr] = a4.z; As[lk + 3][lr] = a4.w;
        Ws[lk + 0][lr] = w4.x; Ws[lk + 1][lr] = w4.y;
        Ws[lk + 2][lr] = w4.z; Ws[lk + 3][lr] = w4.w;
        __syncthreads();
#pragma unroll
        for (int kk = 0; kk < 16; kk++) {
            float4 av = *(const float4*)&As[kk][ty << 2];
            float4 wv = *(const float4*)&Ws[kk][tx << 2];
            acc[0][0] += av.x * wv.x; acc[0][1] += av.x * wv.y;
            acc[0][2] += av.x * wv.z; acc[0][3] += av.x * wv.w;
            acc[1][0] += av.y * wv.x; acc[1][1] += av.y * wv.y;
            acc[1][2] += av.y * wv.z; acc[1][3] += av.y * wv.w;
            acc[2][0] += av.z * wv.x; acc[2][1] += av.z * wv.y;
            acc[2][2] += av.z * wv.z; acc[2][3] += av.z * wv.w;
            acc[3][0] += av.w * wv.x; acc[3][1] += av.w * wv.y;
            acc[3][2] += av.w * wv.z; acc[3][3] += av.w * wv.w;
        }
        __syncthreads();
    }

    const int c0 = col0 + (tx << 2);
    float* Cp = C + (size_t)blockIdx.z * ((size_t)64 * N);
#pragma unroll
    for (int i = 0; i < 4; i++) {
        size_t r = (size_t)(row0 + (ty << 2) + i);
        *(float4*)(Cp + r * N + c0) =
            make_float4(acc[i][0], acc[i][1], acc[i][2], acc[i][3]);
    }
}

// Sum 8 K-split partials + bias (+optional gelu); write at column offset.
template <int ACT>
__global__ __launch_bounds__(256) void reduce8_kernel(
    const float* __restrict__ P, const float* __restrict__ bias,
    float* __restrict__ C, int N, int coff, int CW) {
    int i = blockIdx.x * 256 + threadIdx.x;  // over 64*N
    int row = i / N;
    int col = i - row * N;
    size_t stride = (size_t)64 * N;
    float s = 0.0f;
#pragma unroll
    for (int z = 0; z < 8; z++) s += P[(size_t)z * stride + (size_t)row * N + col];
    s += bias[col];
    if (ACT) s = gelu_exact(s);
    C[(size_t)row * CW + coff + col] = s;
}

// LayerNorm + GELU, in place on bf16 h rows (h already includes bp bias).
__global__ __launch_bounds__(256) void ln_gelu_kernel(
    unsigned short* __restrict__ hc, const float* __restrict__ g,
    const float* __restrict__ bb) {
    __shared__ float sred[4];
    const int tid = threadIdx.x;
    size_t base = (size_t)blockIdx.x * CD;
    float4 x = ld4(hc + base + tid * 4);
    float s = x.x + x.y + x.z + x.w;
#pragma unroll
    for (int off = 32; off; off >>= 1) s += __shfl_down(s, off, 64);
    if ((tid & 63) == 0) sred[tid >> 6] = s;
    __syncthreads();
    float mu = (sred[0] + sred[1] + sred[2] + sred[3]) * (1.0f / 1024.0f);
    float d0 = x.x - mu, d1 = x.y - mu, d2 = x.z - mu, d3 = x.w - mu;
    float sq = d0 * d0 + d1 * d1 + d2 * d2 + d3 * d3;
    __syncthreads();
#pragma unroll
    for (int off = 32; off; off >>= 1) sq += __shfl_down(sq, off, 64);
    if ((tid & 63) == 0) sred[tid >> 6] = sq;
    __syncthreads();
    float var = (sred[0] + sred[1] + sred[2] + sred[3]) * (1.0f / 1024.0f);
    float rs = 1.0f / sqrtf(var + 1e-5f);
    float4 gv = ((const float4*)g)[tid];
    float4 bv = ((const float4*)bb)[tid];
    float4 o;
    o.x = gelu_exact(d0 * rs * gv.x + bv.x);
    o.y = gelu_exact(d1 * rs * gv.y + bv.y);
    o.z = gelu_exact(d2 * rs * gv.z + bv.z);
    o.w = gelu_exact(d3 * rs * gv.w + bv.w);
    st4(hc + base + tid * 4, o);
}

// zbuf[:,0,:]=z_init, rest 0; hist = broadcast hist_init.
__global__ __launch_bounds__(256) void init_kernel(
    const float* __restrict__ z_init, const float* __restrict__ hist_init,
    float* __restrict__ zbuf, float* __restrict__ hist) {
    int i = blockIdx.x * 256 + threadIdx.x;
    if (i < CB * CTP1 * CD) {
        int rem = i % (CTP1 * CD);
        int ts = rem / CD;
        int d = rem - ts * CD;
        zbuf[i] = (ts == 0) ? z_init[d] : 0.0f;
    }
    if (i < CB * CD * CM) {
        hist[i] = hist_init[i % (CD * CM)];
    }
}

// s_act, s_out for step t; also copies z = zbuf[:,t,:] into combined[:, :D].
__global__ __launch_bounds__(256) void sync_kernel(
    const float* __restrict__ zbuf,
    const float* __restrict__ decay_a, const float* __restrict__ decay_o,
    const int* __restrict__ iia, const int* __restrict__ jja,
    const int* __restrict__ iio, const int* __restrict__ jjo,
    float* __restrict__ s_act, float* __restrict__ s_out,
    float* __restrict__ combined, int t) {
    int b = blockIdx.x >> 2;
    int sg = ((blockIdx.x & 3) << 8) + threadIdx.x;  // 0..1023
    const float* zb = zbuf + (size_t)b * CTP1 * CD;
    combined[(size_t)b * (2 * CD) + sg] = zb[(size_t)t * CD + sg];
    float soft;
    int ii, jj;
    if (sg < CDA) {
        soft = softplusf(decay_a[sg]);
        ii = iia[sg]; jj = jja[sg];
    } else {
        int s2 = sg - CDA;
        soft = softplusf(decay_o[s2]);
        ii = iio[s2]; jj = jjo[s2];
    }
    float num = 0.0f, den = 0.0f;
    for (int ts = 0; ts <= t; ts++) {
        float w = expf(-soft * (float)(t - ts));
        num += zb[(size_t)ts * CD + ii] * zb[(size_t)ts * CD + jj] * w;
        den += w * w;
    }
    float val = num / sqrtf(den + 1e-8f);
    if (sg < CDA) s_act[b * CDA + sg] = val;
    else s_out[b * CDO + (sg - CDA)] = val;
}

// One block per (b,h): scores over S=512, softmax, P@V. k/v are bf16.
__global__ __launch_bounds__(256) void attn_kernel(
    const float* __restrict__ qh, const unsigned short* __restrict__ kb,
    const unsigned short* __restrict__ vb, float* __restrict__ attn_out) {
    __shared__ float qv[CDH];
    __shared__ float att[CS];
    __shared__ float red[4];
    __shared__ float pv[2][CDH];
    const int tid = threadIdx.x;
    const int b = blockIdx.x >> 3, h = blockIdx.x & 7;
    if (tid < CDH) qv[tid] = qh[(size_t)b * CD + h * CDH + tid];
    __syncthreads();
    const float scale = 0.08838834764831845f;  // 1/sqrt(128)
    float sc0, sc1;
    {
        const unsigned short* kr0 = kb + ((size_t)(b * CS) + tid) * CD + h * CDH;
        const unsigned short* kr1 = kr0 + (size_t)256 * CD;
        float a0 = 0.0f, a1 = 0.0f;
#pragma unroll 8
        for (int d2 = 0; d2 < CDH; d2 += 4) {
            float4 k0 = ld4(kr0 + d2);
            float4 k1 = ld4(kr1 + d2);
            a0 += k0.x * qv[d2] + k0.y * qv[d2 + 1] + k0.z * qv[d2 + 2] + k0.w * qv[d2 + 3];
            a1 += k1.x * qv[d2] + k1.y * qv[d2 + 1] + k1.z * qv[d2 + 2] + k1.w * qv[d2 + 3];
        }
        sc0 = a0 * scale;
        sc1 = a1 * scale;
    }
    float mx = fmaxf(sc0, sc1);
#pragma unroll
    for (int off = 32; off; off >>= 1) mx = fmaxf(mx, __shfl_down(mx, off, 64));
    if ((tid & 63) == 0) red[tid >> 6] = mx;
    __syncthreads();
    mx = fmaxf(fmaxf(red[0], red[1]), fmaxf(red[2], red[3]));
    float e0 = expf(sc0 - mx), e1 = expf(sc1 - mx);
    att[tid] = e0;
    att[tid + 256] = e1;
    float sm = e0 + e1;
#pragma unroll
    for (int off = 32; off; off >>= 1) sm += __shfl_down(sm, off, 64);
    __syncthreads();
    if ((tid & 63) == 0) red[tid >> 6] = sm;
    __syncthreads();
    float inv = 1.0f / (red[0] + red[1] + red[2] + red[3]);
    const int d = tid & 127, half = tid >> 7;
    const unsigned short* vr = vb + ((size_t)(b * CS) + half * 256) * CD + h * CDH + d;
    float acc = 0.0f;
    for (int s2 = 0; s2 < 256; s2++) {
        acc += att[half * 256 + s2] * us2f(vr[(size_t)s2 * CD]);
    }
    pv[half][d] = acc;
    __syncthreads();
    if (tid < CDH)
        attn_out[(size_t)b * CD + h * CDH + tid] = (pv[0][tid] + pv[1][tid]) * inv;
}

// hist shift+append, 3 tiny per-(b,d) einsums, write z_new into zbuf[:,t+1,:].
__global__ __launch_bounds__(256) void neuron_kernel(
    const float* __restrict__ pre, float* __restrict__ hist,
    const float* __restrict__ Wn1, const float* __restrict__ bn1,
    const float* __restrict__ Wn2, const float* __restrict__ bn2,
    const float* __restrict__ Wn3, const float* __restrict__ bn3,
    float* __restrict__ zbuf, int t) {
    int idx = blockIdx.x * 256 + threadIdx.x;  // 0..65535 = (b,d)
    int b = idx >> 10, d = idx & 1023;
    float hv[CM];
    float* hp = hist + (size_t)idx * CM;
#pragma unroll
    for (int m = 0; m < CM - 1; m++) hv[m] = hp[m + 1];
    hv[CM - 1] = pre[idx];
#pragma unroll
    for (int m = 0; m < CM; m++) hp[m] = hv[m];
    float x1[CH];
#pragma unroll
    for (int hh = 0; hh < CH; hh++) {
        const float* w = Wn1 + ((size_t)d * CH + hh) * CM;
        float s = bn1[d * CH + hh];
#pragma unroll
        for (int m = 0; m < CM; m++) s += hv[m] * w[m];
        x1[hh] = gelu_exact(s);
    }
    float x2[CH];
#pragma unroll
    for (int g = 0; g < CH; g++) {
        float s = bn2[d * CH + g];
#pragma unroll
        for (int hh = 0; hh < CH; hh++) s += x1[hh] * Wn2[((size_t)d * CH + g) * CH + hh];
        x2[g] = gelu_exact(s);
    }
    float z = bn3[d];
#pragma unroll
    for (int hh = 0; hh < CH; hh++) z += x2[hh] * Wn3[d * CH + hh];
    zbuf[((size_t)b * CTP1 + (t + 1)) * CD + d] = z;
}

// One block per b: hh = gelu(s_out@Wh1.T+bh1); out[b,t] = hh@Wh2.T + bh2.
__global__ __launch_bounds__(256) void logits_kernel(
    const float* __restrict__ s_out, const float* __restrict__ Wh1,
    const float* __restrict__ bh1, const float* __restrict__ Wh2,
    const float* __restrict__ bh2, float* __restrict__ out, int t) {
    __shared__ float so[CDO];
    __shared__ float hh[CDO];
    __shared__ float red[4];
    const int b = blockIdx.x, tid = threadIdx.x;
    ((float2*)so)[tid] = ((const float2*)(s_out + (size_t)b * CDO))[tid];
    __syncthreads();
#pragma unroll
    for (int p = 0; p < 2; p++) {
        int j = tid + p * 256;
        const float* w = Wh1 + (size_t)j * CDO;
        float s = bh1[j];
#pragma unroll 4
        for (int k2 = 0; k2 < CDO; k2 += 4) {
            float4 wv = *(const float4*)(w + k2);
            s += wv.x * so[k2] + wv.y * so[k2 + 1] + wv.z * so[k2 + 2] + wv.w * so[k2 + 3];
        }
        hh[j] = gelu_exact(s);
    }
    __syncthreads();
    float part = hh[tid] * Wh2[tid] + hh[tid + 256] * Wh2[tid + 256];
#pragma unroll
    for (int off = 32; off; off >>= 1) part += __shfl_down(part, off, 64);
    if ((tid & 63) == 0) red[tid >> 6] = part;
    __syncthreads();
    if (tid == 0) out[b * CT + t] = red[0] + red[1] + red[2] + red[3] + bh2[0];
}

// Writes v to all outputs; v encodes ws_size in MB so a failure is decodable.
__global__ void sentinel_kernel(float* out, float v) {
    int i = blockIdx.x * 256 + threadIdx.x;
    if (i < CB * CT) out[i] = v;
}

extern "C" void kernel_launch(void* const* d_in, const int* in_sizes, int n_in,
                              void* d_out, int out_size, void* d_ws, size_t ws_size,
                              hipStream_t stream) {
    const float* emb = (const float*)d_in[0];
    const float* Wp = (const float*)d_in[1];
    const float* bp = (const float*)d_in[2];
    const float* ln_g = (const float*)d_in[3];
    const float* ln_b = (const float*)d_in[4];
    const float* decay_a = (const float*)d_in[5];
    const float* decay_o = (const float*)d_in[6];
    const float* Wq = (const float*)d_in[7];
    const float* bq = (const float*)d_in[8];
    const float* Wqkv = (const float*)d_in[9];
    const float* bqkv = (const float*)d_in[10];
    const float* Wo = (const float*)d_in[11];
    const float* bo = (const float*)d_in[12];
    const float* Ws1 = (const float*)d_in[13];
    const float* bs1 = (const float*)d_in[14];
    const float* Ws2 = (const float*)d_in[15];
    const float* bs2 = (const float*)d_in[16];
    const float* Wn1 = (const float*)d_in[17];
    const float* bn1 = (const float*)d_in[18];
    const float* Wn2 = (const float*)d_in[19];
    const float* bn2 = (const float*)d_in[20];
    const float* Wn3 = (const float*)d_in[21];
    const float* bn3 = (const float*)d_in[22];
    const float* Wh1 = (const float*)d_in[23];
    const float* bh1 = (const float*)d_in[24];
    const float* Wh2 = (const float*)d_in[25];
    const float* bh2 = (const float*)d_in[26];
    const float* z_init = (const float*)d_in[27];
    const float* hist_init = (const float*)d_in[28];
    const int* iia = (const int*)d_in[29];
    const int* jja = (const int*)d_in[30];
    const int* iio = (const int*)d_in[31];
    const int* jjo = (const int*)d_in[32];
    float* out = (float*)d_out;

    char* wsb = (char*)d_ws;
    size_t off = 0;
    auto alloc = [&](size_t bytes) {
        void* p = wsb + off;
        off += (bytes + 255) & ~(size_t)255;
        return p;
    };
    unsigned short* ctx  = (unsigned short*)alloc((size_t)CB * CS * CD * 2);
    unsigned short* kbuf = (unsigned short*)alloc((size_t)CB * CS * CD * 2);
    unsigned short* vbuf = (unsigned short*)alloc((size_t)CB * CS * CD * 2);
    float* zbuf = (float*)alloc((size_t)CB * CTP1 * CD * 4);
    float* hist = (float*)alloc((size_t)CB * CD * CM * 4);
    float* s_act = (float*)alloc((size_t)CB * CDA * 4);
    float* s_out = (float*)alloc((size_t)CB * CDO * 4);
    float* qbuf = (float*)alloc((size_t)CB * CD * 4);
    float* qh = (float*)alloc((size_t)CB * CD * 4);
    float* attn_out = (float*)alloc((size_t)CB * CD * 4);
    float* combined = (float*)alloc((size_t)CB * 2 * CD * 4);
    float* pre1 = (float*)alloc((size_t)CB * 2 * CD * 4);
    float* pre = (float*)alloc((size_t)CB * CD * 4);
    float* P = (float*)alloc((size_t)8 * 64 * 2048 * 4);

    if (off > ws_size) {
        sentinel_kernel<<<dim3(4), dim3(256), 0, stream>>>(out, -(float)(ws_size >> 20));
        return;
    }

    // ---- Phase A (bf16 MFMA) ----
    // h = emb @ Wp.T + bp  (fp32 inputs converted to bf16 during staging)
    gemm_mfma<float><<<dim3(CB * CS / 128, CD / 128), 256, 0, stream>>>(
        emb, Wp, bp, ctx, CD, CDE);
    ln_gelu_kernel<<<dim3(CB * CS), 256, 0, stream>>>(ctx, ln_g, ln_b);
    gemm_mfma<unsigned short><<<dim3(CB * CS / 128, CD / 128), 256, 0, stream>>>(
        ctx, Wqkv + (size_t)CD * CD, bqkv + CD, kbuf, CD, CD);
    gemm_mfma<unsigned short><<<dim3(CB * CS / 128, CD / 128), 256, 0, stream>>>(
        ctx, Wqkv + (size_t)2 * CD * CD, bqkv + 2 * CD, vbuf, CD, CD);
    init_kernel<<<dim3(4352), 256, 0, stream>>>(z_init, hist_init, zbuf, hist);

    // ---- Phase B: 16 sequential steps ----
    for (int t = 0; t < CT; t++) {
        sync_kernel<<<dim3(256), 256, 0, stream>>>(zbuf, decay_a, decay_o, iia, jja, iio, jjo,
                                                   s_act, s_out, combined, t);
        // q = s_act @ Wq.T + bq
        gemm_tn<<<dim3(1, 16, 8), 256, 0, stream>>>(s_act, Wq, nullptr, P, CD, CDA, CDA / 8);
        reduce8_kernel<0><<<dim3(256), 256, 0, stream>>>(P, bq, qbuf, CD, 0, CD);
        // qh = q @ Wq3.T + bq3
        gemm_tn<<<dim3(1, 16, 8), 256, 0, stream>>>(qbuf, Wqkv, nullptr, P, CD, CD, CD / 8);
        reduce8_kernel<0><<<dim3(256), 256, 0, stream>>>(P, bqkv, qh, CD, 0, CD);
        // attention
        attn_kernel<<<dim3(CB * CNH), 256, 0, stream>>>(qh, kbuf, vbuf, attn_out);
        // attn_out @ Wo.T + bo -> combined[:, D:]
        gemm_tn<<<dim3(1, 16, 8), 256, 0, stream>>>(attn_out, Wo, nullptr, P, CD, CD, CD / 8);
        reduce8_kernel<0><<<dim3(256), 256, 0, stream>>>(P, bo, combined, CD, CD, 2 * CD);
        // pre1 = gelu(combined @ Ws1.T + bs1)
        gemm_tn<<<dim3(1, 32, 8), 256, 0, stream>>>(combined, Ws1, nullptr, P, 2 * CD, 2 * CD, 2 * CD / 8);
        reduce8_kernel<1><<<dim3(512), 256, 0, stream>>>(P, bs1, pre1, 2 * CD, 0, 2 * CD);
        // pre = pre1 @ Ws2.T + bs2
        gemm_tn<<<dim3(1, 16, 8), 256, 0, stream>>>(pre1, Ws2, nullptr, P, CD, 2 * CD, 2 * CD / 8);
        reduce8_kernel<0><<<dim3(256), 256, 0, stream>>>(P, bs2, pre, CD, 0, CD);
        // hist update + neuron MLP -> zbuf[:, t+1]
        neuron_kernel<<<dim3(256), 256, 0, stream>>>(pre, hist, Wn1, bn1, Wn2, bn2, Wn3, bn3, zbuf, t);
        // logits for this step
        logits_kernel<<<dim3(CB), 256, 0, stream>>>(s_out, Wh1, bh1, Wh2, bh2, out, t);
    }
}